// Round 5
// baseline (1767.115 us; speedup 1.0000x reference)
//
#include <hip/hip_runtime.h>
#include <math.h>

#define Bsz 32
#define Lseq 1024
#define CHUNK 64
#define NCHUNK 16

__device__ __forceinline__ float fsig(float x) {
    return __builtin_amdgcn_rcpf(1.f + __expf(-x));
}
// Accurate fast tanh: Taylor for small |x| (avoids catastrophic cancellation
// in the exp form at x~1e-7, which killed R2), exp form for large |x|.
__device__ __forceinline__ float ftanh(float x) {
    float x2 = x * x;
    float poly = x * (1.f - 0.333333333f * x2 + 0.133333333f * x2 * x2);
    float big = 1.f - 2.f * __builtin_amdgcn_rcpf(1.f + __expf(2.f * x));
    return (x2 < 0.0025f) ? poly : big;
}
__device__ __forceinline__ float fsilu(float x) {
    return x * __builtin_amdgcn_rcpf(1.f + __expf(-x));
}

// ---------------- precompute: folded weight products ----------------
__global__ void k_pre(const float* w_proj, const float* b_proj, const float* w_inproj,
                      const float* A_log, const float* w_ih, const float* w_out,
                      const float* b_ih, const float* b_hh,
                      float* Ab, float* Minp, float* cinp, float* M2, float* c2) {
    int idx = blockIdx.x * 256 + threadIdx.x;
    if (idx < 4096) {
        Ab[idx] = -expf(A_log[idx]);
    } else if (idx < 4096 + 6144) {
        int j = idx - 4096; int o = j / 12; int i = j - o * 12;
        float s = 0.f;
        for (int k = 0; k < 128; ++k) s += w_inproj[o*128+k] * w_proj[k*12+i];
        Minp[j] = s;
    } else if (idx < 4096 + 6144 + 512) {
        int o = idx - (4096 + 6144);
        float s = 0.f;
        for (int k = 0; k < 128; ++k) s += w_inproj[o*128+k] * b_proj[k];
        cinp[o] = s;
    } else if (idx < 4096 + 6144 + 512 + 131072) {
        int j = idx - (4096 + 6144 + 512);
        int o = j >> 8; int dd = j & 255;
        float s = 0.f;
        for (int k = 0; k < 128; ++k) s += w_ih[o*128+k] * w_out[k*256+dd];
        M2[j] = s;
    } else if (idx < 4096 + 6144 + 512 + 131072 + 512) {
        int o = idx - (4096 + 6144 + 512 + 131072);
        c2[o] = b_ih[o] + b_hh[o];
    }
}

// ---------------- k_front: fused inproj + depthwise conv + SiLU ----------------
__global__ void __launch_bounds__(256) k_front(const float* __restrict__ x,
                       const float* __restrict__ Minp, const float* __restrict__ cinp,
                       const float* __restrict__ conv_w, const float* __restrict__ conv_b,
                       float* __restrict__ uc, float* __restrict__ zb) {
    __shared__ float xs[67*12];
    int b = blockIdx.x >> 4;
    int c = blockIdx.x & 15;
    int d = threadIdx.x;
    int t0 = c * 64;
    for (int i = d; i < 67*12; i += 256) {
        int trel = i / 12;
        int t = t0 - 3 + trel;
        xs[i] = (t >= 0) ? x[(b*1024 + t)*12 + (i - trel*12)] : 0.f;
    }
    __syncthreads();
    float mu[12], mz[12];
#pragma unroll
    for (int i = 0; i < 12; ++i) { mu[i] = Minp[d*12 + i]; mz[i] = Minp[(256+d)*12 + i]; }
    float cu = cinp[d], cz = cinp[256 + d];
    float cw0 = conv_w[d*4+0], cw1 = conv_w[d*4+1], cw2 = conv_w[d*4+2], cw3 = conv_w[d*4+3];
    float cb = conv_b[d];
    float r0 = 0.f, r1 = 0.f, r2 = 0.f;
#pragma unroll
    for (int k = 0; k < 3; ++k) {
        int t = t0 - 3 + k;
        float v = 0.f;
        if (t >= 0) {
            const float* xr = &xs[k*12];
            v = cu;
#pragma unroll
            for (int i = 0; i < 12; ++i) v += mu[i]*xr[i];
        }
        r0 = r1; r1 = r2; r2 = v;
    }
    for (int t = t0; t < t0 + 64; ++t) {
        const float* xr = &xs[(t - t0 + 3)*12];
        float u = cu, z = cz;
#pragma unroll
        for (int i = 0; i < 12; ++i) { u += mu[i]*xr[i]; z += mz[i]*xr[i]; }
        float cv = cb + cw0*r0 + cw1*r1 + cw2*r2 + cw3*u;
        uc[(b*1024 + t)*256 + d] = fsilu(cv);
        zb[(b*1024 + t)*256 + d] = z;
        r0 = r1; r1 = r2; r2 = u;
    }
}

// ---------------- k3: xdbc = uc @ w_xproj^T; dt = softplus(...) ----------------
__global__ void __launch_bounds__(256) k_xproj(const float* __restrict__ uc,
                        const float* __restrict__ w_xproj, const float* __restrict__ w_dt,
                        const float* __restrict__ b_dt,
                        float* __restrict__ dtb, float* __restrict__ Bm, float* __restrict__ Cm) {
    __shared__ float ur[256];
    __shared__ float xd[40];
    int tok = blockIdx.x;
    int tid = threadIdx.x;
    ur[tid] = uc[tok*256 + tid];
    __syncthreads();
    int j = tid >> 2, q = tid & 3;
    float s = 0.f;
    if (j < 40) {
        const float* wr = w_xproj + j*256 + q*64;
        const float* uq = ur + q*64;
#pragma unroll 8
        for (int k = 0; k < 64; ++k) s += wr[k] * uq[k];
    }
    s += __shfl_xor(s, 1);
    s += __shfl_xor(s, 2);
    if (j < 40 && q == 0) {
        xd[j] = s;
        if (j >= 8 && j < 24)      Bm[tok*16 + (j - 8)]  = s;
        else if (j >= 24)          Cm[tok*16 + (j - 24)] = s;
    }
    __syncthreads();
    float r = b_dt[tid];
    const float* wd = w_dt + tid*8;
#pragma unroll
    for (int jj = 0; jj < 8; ++jj) r += wd[jj] * xd[jj];
    r = (r > 20.f) ? r : log1pf(expf(r));   // softplus
    dtb[tok*256 + tid] = r;
}

// ---------------- SSM chunked scan ----------------
__global__ void __launch_bounds__(256) k_ssm_p1(const float* __restrict__ dtb,
                        const float* __restrict__ uc, const float* __restrict__ Bm,
                        const float* __restrict__ Ab,
                        float* __restrict__ h0end, float* __restrict__ Ssum) {
    __shared__ float Bs[CHUNK*16];
    int b = blockIdx.x >> 4;
    int c = blockIdx.x & 15;
    int d = threadIdx.x;
    int t0 = c * CHUNK;
    {
        const float* src = Bm + (b*1024 + t0) * 16;
        for (int i = d; i < CHUNK*16; i += 256) Bs[i] = src[i];
    }
    __syncthreads();
    float a[16], h[16];
#pragma unroll
    for (int s = 0; s < 16; ++s) { a[s] = Ab[d*16+s]; h[s] = 0.f; }
    float S = 0.f;
    const float* dtp = dtb + (b*1024 + t0)*256 + d;
    const float* up  = uc  + (b*1024 + t0)*256 + d;
    float dtv = dtp[0], uv = up[0];
    for (int t = 0; t < CHUNK; ++t) {
        float dtn = 0.f, un = 0.f;
        if (t < CHUNK-1) { dtn = dtp[(t+1)*256]; un = up[(t+1)*256]; }
        float dtu = dtv * uv;
        S += dtv;
#pragma unroll
        for (int s = 0; s < 16; ++s) {
            float dA = __expf(dtv * a[s]);
            h[s] = h[s]*dA + dtu * Bs[t*16+s];
        }
        dtv = dtn; uv = un;
    }
    float* he = h0end + ((b*256 + d)*16 + c)*16;
#pragma unroll
    for (int s = 0; s < 16; ++s) he[s] = h[s];
    Ssum[(b*256 + d)*16 + c] = S;
}

__global__ void k_ssm_p2(const float* __restrict__ h0end, const float* __restrict__ Ssum,
                         const float* __restrict__ Ab, float* __restrict__ hinit) {
    int gid = blockIdx.x * 256 + threadIdx.x;   // 131072 = 32*256*16
    int s = gid & 15;
    int bd = gid >> 4;
    int d = bd & 255;
    float a = Ab[d*16 + s];
    float carry = 0.f;
    const float* he = h0end + bd * 256;
    float* hi = hinit + bd * 256;
    const float* Sp = Ssum + bd * 16;
    for (int c = 0; c < 16; ++c) {
        hi[c*16 + s] = carry;
        carry = he[c*16 + s] + __expf(a * Sp[c]) * carry;
    }
}

__global__ void __launch_bounds__(256) k_ssm_p3(const float* __restrict__ dtb,
                        const float* __restrict__ uc, const float* __restrict__ zb,
                        const float* __restrict__ Bm, const float* __restrict__ Cm,
                        const float* __restrict__ Ab, const float* __restrict__ Dskip,
                        const float* __restrict__ hinit, float* __restrict__ yg) {
    __shared__ float Bs[CHUNK*16];
    __shared__ float Cs[CHUNK*16];
    int b = blockIdx.x >> 4;
    int c = blockIdx.x & 15;
    int d = threadIdx.x;
    int t0 = c * CHUNK;
    {
        const float* srcB = Bm + (b*1024 + t0) * 16;
        const float* srcC = Cm + (b*1024 + t0) * 16;
        for (int i = d; i < CHUNK*16; i += 256) { Bs[i] = srcB[i]; Cs[i] = srcC[i]; }
    }
    __syncthreads();
    float a[16], h[16];
    const float* hi = hinit + ((b*256 + d)*16 + c)*16;
#pragma unroll
    for (int s = 0; s < 16; ++s) { a[s] = Ab[d*16+s]; h[s] = hi[s]; }
    float Dv = Dskip[d];
    const float* dtp = dtb + (b*1024 + t0)*256 + d;
    const float* up  = uc  + (b*1024 + t0)*256 + d;
    const float* zp  = zb  + (b*1024 + t0)*256 + d;
    float* yp = yg + (b*1024 + t0)*256 + d;
    float dtv = dtp[0], uv = up[0], zv = zp[0];
    for (int t = 0; t < CHUNK; ++t) {
        float dtn = 0.f, un = 0.f, zn = 0.f;
        if (t < CHUNK-1) { dtn = dtp[(t+1)*256]; un = up[(t+1)*256]; zn = zp[(t+1)*256]; }
        float dtu = dtv * uv;
        float y = 0.f;
#pragma unroll
        for (int s = 0; s < 16; ++s) {
            float dA = __expf(dtv * a[s]);
            h[s] = h[s]*dA + dtu * Bs[t*16+s];
            y += h[s] * Cs[t*16+s];
        }
        yp[t*256] = (y + uv * Dv) * fsilu(zv);
        dtv = dtn; uv = un; zv = zn;
    }
}

// ---------------- k5: xg = yg @ M2^T + c2  (32768x512, K=256) ----------------
__global__ void __launch_bounds__(256) k_xg(const float* __restrict__ yg,
                      const float* __restrict__ M2, const float* __restrict__ c2,
                      float* __restrict__ xg) {
    __shared__ float ytile[16][256];
    int tokbase = blockIdx.x * 16;
    int tid = threadIdx.x;
    for (int r = 0; r < 16; ++r) ytile[r][tid] = yg[(tokbase + r)*256 + tid];
    __syncthreads();
    int o0 = tid, o1 = tid + 256;
    float acc0[16], acc1[16];
    float cc0 = c2[o0], cc1 = c2[o1];
#pragma unroll
    for (int r = 0; r < 16; ++r) { acc0[r] = cc0; acc1[r] = cc1; }
    const float4* m0 = (const float4*)(M2 + o0*256);
    const float4* m1 = (const float4*)(M2 + o1*256);
    for (int k4 = 0; k4 < 64; ++k4) {
        float4 w0 = m0[k4];
        float4 w1 = m1[k4];
#pragma unroll
        for (int r = 0; r < 16; ++r) {
            float4 v = *(const float4*)&ytile[r][k4*4];
            acc0[r] += v.x*w0.x + v.y*w0.y + v.z*w0.z + v.w*w0.w;
            acc1[r] += v.x*w1.x + v.y*w1.y + v.z*w1.z + v.w*w1.w;
        }
    }
    for (int r = 0; r < 16; ++r) {
        xg[(tokbase + r)*512 + o0] = acc0[r];
        xg[(tokbase + r)*512 + o1] = acc1[r];
    }
}

// ---------------- k6: LSTM (one block per batch) + FC head ----------------
// 512 threads, thread = gate output o. Full 128-wide weight row in 32 NAMED
// float4 registers. __launch_bounds__(512, 1): R4's (512,2) produced a
// 128-VGPR budget (VGPR_Count=124 -> weights spilled); with min-occupancy 1
// the budget is 256 VGPRs and the ~150 live registers fit without spilling.
#define LSTM_LOADW(i) float4 W##i = wr[i];
#define LSTM_DOT(i, acc) { float4 hv = h4[i]; \
    acc = fmaf(hv.x, W##i.x, acc); acc = fmaf(hv.y, W##i.y, acc); \
    acc = fmaf(hv.z, W##i.z, acc); acc = fmaf(hv.w, W##i.w, acc); }

__global__ void __launch_bounds__(512, 1) k_lstm(const float* __restrict__ xg,
                       const float* __restrict__ w_hh,
                       const float* __restrict__ w_fc1, const float* __restrict__ b_fc1,
                       const float* __restrict__ w_fc2, const float* __restrict__ b_fc2,
                       float* __restrict__ out) {
    __shared__ float hbuf[128];
    __shared__ float gbuf[512];
    int b = blockIdx.x;
    int tid = threadIdx.x;   // gate output index o
    const float4* wr = (const float4*)(w_hh + tid*128);
    LSTM_LOADW(0)  LSTM_LOADW(1)  LSTM_LOADW(2)  LSTM_LOADW(3)
    LSTM_LOADW(4)  LSTM_LOADW(5)  LSTM_LOADW(6)  LSTM_LOADW(7)
    LSTM_LOADW(8)  LSTM_LOADW(9)  LSTM_LOADW(10) LSTM_LOADW(11)
    LSTM_LOADW(12) LSTM_LOADW(13) LSTM_LOADW(14) LSTM_LOADW(15)
    LSTM_LOADW(16) LSTM_LOADW(17) LSTM_LOADW(18) LSTM_LOADW(19)
    LSTM_LOADW(20) LSTM_LOADW(21) LSTM_LOADW(22) LSTM_LOADW(23)
    LSTM_LOADW(24) LSTM_LOADW(25) LSTM_LOADW(26) LSTM_LOADW(27)
    LSTM_LOADW(28) LSTM_LOADW(29) LSTM_LOADW(30) LSTM_LOADW(31)
    float cstate = 0.f;
    if (tid < 128) hbuf[tid] = 0.f;
    __syncthreads();
    const float* xgb = xg + (size_t)b * 1024 * 512;
    float gx = xgb[tid];
    for (int t = 0; t < 1024; ++t) {
        float gxn = (t < 1023) ? xgb[(t+1)*512 + tid] : 0.f;   // prefetch next step
        const float4* h4 = (const float4*)hbuf;
        float a0 = 0.f, a1 = 0.f, a2 = 0.f, a3 = 0.f;
        LSTM_DOT(0,  a0) LSTM_DOT(8,  a1) LSTM_DOT(16, a2) LSTM_DOT(24, a3)
        LSTM_DOT(1,  a0) LSTM_DOT(9,  a1) LSTM_DOT(17, a2) LSTM_DOT(25, a3)
        LSTM_DOT(2,  a0) LSTM_DOT(10, a1) LSTM_DOT(18, a2) LSTM_DOT(26, a3)
        LSTM_DOT(3,  a0) LSTM_DOT(11, a1) LSTM_DOT(19, a2) LSTM_DOT(27, a3)
        LSTM_DOT(4,  a0) LSTM_DOT(12, a1) LSTM_DOT(20, a2) LSTM_DOT(28, a3)
        LSTM_DOT(5,  a0) LSTM_DOT(13, a1) LSTM_DOT(21, a2) LSTM_DOT(29, a3)
        LSTM_DOT(6,  a0) LSTM_DOT(14, a1) LSTM_DOT(22, a2) LSTM_DOT(30, a3)
        LSTM_DOT(7,  a0) LSTM_DOT(15, a1) LSTM_DOT(23, a2) LSTM_DOT(31, a3)
        gbuf[tid] = gx + ((a0 + a1) + (a2 + a3));
        __syncthreads();
        if (tid < 128) {
            float ig = fsig(gbuf[tid]);
            float fg = fsig(gbuf[tid+128]);
            float gg = ftanh(gbuf[tid+256]);
            float og = fsig(gbuf[tid+384]);
            cstate = fg*cstate + ig*gg;
            hbuf[tid] = og * ftanh(cstate);
        }
        __syncthreads();
        gx = gxn;
    }
    // FC head
    if (tid < 128) {
        float s = b_fc1[tid];
        const float* wf = w_fc1 + tid*128;
#pragma unroll 4
        for (int k = 0; k < 128; ++k) s += wf[k] * hbuf[k];
        gbuf[tid] = fmaxf(s, 0.f);
    }
    __syncthreads();
    if (tid < 5) {
        float s = b_fc2[tid];
        const float* wf = w_fc2 + tid*128;
        for (int k = 0; k < 128; ++k) s += wf[k] * gbuf[k];
        out[b*5 + tid] = s;
    }
}

// ---------------- launch ----------------
extern "C" void kernel_launch(void* const* d_in, const int* in_sizes, int n_in,
                              void* d_out, int out_size, void* d_ws, size_t ws_size,
                              hipStream_t stream) {
    const float* x        = (const float*)d_in[0];
    const float* w_proj   = (const float*)d_in[1];
    const float* b_proj   = (const float*)d_in[2];
    const float* w_inproj = (const float*)d_in[3];
    const float* conv_w   = (const float*)d_in[4];
    const float* conv_b   = (const float*)d_in[5];
    const float* w_xproj  = (const float*)d_in[6];
    const float* w_dt     = (const float*)d_in[7];
    const float* b_dt     = (const float*)d_in[8];
    const float* A_log    = (const float*)d_in[9];
    const float* Dskip    = (const float*)d_in[10];
    const float* w_out    = (const float*)d_in[11];
    const float* w_ih     = (const float*)d_in[12];
    const float* w_hh     = (const float*)d_in[13];
    const float* b_ih     = (const float*)d_in[14];
    const float* b_hh     = (const float*)d_in[15];
    const float* w_fc1    = (const float*)d_in[16];
    const float* b_fc1    = (const float*)d_in[17];
    const float* w_fc2    = (const float*)d_in[18];
    const float* b_fc2    = (const float*)d_in[19];
    float* outp = (float*)d_out;

    float* ws = (float*)d_ws;
    size_t off = 0;
    float* uc   = ws + off; off += 8388608;   // xg aliases uc+zb after p3
    float* zb   = ws + off; off += 8388608;
    float* dtb  = ws + off; off += 8388608;
    float* yg   = ws + off; off += 8388608;
    float* Bm   = ws + off; off += 524288;
    float* Cm   = ws + off; off += 524288;
    float* Ab   = ws + off; off += 4096;
    float* Minp = ws + off; off += 6144;
    float* cinp = ws + off; off += 512;
    float* M2   = ws + off; off += 131072;
    float* c2   = ws + off; off += 512;
    float* h0end = ws + off; off += 2097152;
    float* Ssum  = ws + off; off += 131072;
    float* hinit = ws + off; off += 2097152;
    float* xg = uc;    // alias: spans uc+zb (16.7M floats), both dead after ssm_p3

    k_pre<<<556, 256, 0, stream>>>(w_proj, b_proj, w_inproj, A_log, w_ih, w_out,
                                   b_ih, b_hh, Ab, Minp, cinp, M2, c2);
    k_front<<<512, 256, 0, stream>>>(x, Minp, cinp, conv_w, conv_b, uc, zb);
    k_xproj<<<32768, 256, 0, stream>>>(uc, w_xproj, w_dt, b_dt, dtb, Bm, Cm);
    k_ssm_p1<<<512, 256, 0, stream>>>(dtb, uc, Bm, Ab, h0end, Ssum);
    k_ssm_p2<<<512, 256, 0, stream>>>(h0end, Ssum, Ab, hinit);
    k_ssm_p3<<<512, 256, 0, stream>>>(dtb, uc, zb, Bm, Cm, Ab, Dskip, hinit, yg);
    k_xg<<<2048, 256, 0, stream>>>(yg, M2, c2, xg);
    k_lstm<<<32, 512, 0, stream>>>(xg, w_hh, w_fc1, b_fc1, w_fc2, b_fc2, outp);
}

// Round 6
// 1667.431 us; speedup vs baseline: 1.0598x; 1.0598x over previous
//
#include <hip/hip_runtime.h>
#include <math.h>

#define Bsz 32
#define Lseq 1024
#define CHUNK 64
#define NCHUNK 16

__device__ __forceinline__ float fsig(float x) {
    return __builtin_amdgcn_rcpf(1.f + __expf(-x));
}
// Accurate fast tanh: Taylor for small |x| (avoids catastrophic cancellation
// in the exp form at x~1e-7, which killed R2), exp form for large |x|.
__device__ __forceinline__ float ftanh(float x) {
    float x2 = x * x;
    float poly = x * (1.f - 0.333333333f * x2 + 0.133333333f * x2 * x2);
    float big = 1.f - 2.f * __builtin_amdgcn_rcpf(1.f + __expf(2.f * x));
    return (x2 < 0.0025f) ? poly : big;
}
__device__ __forceinline__ float fsilu(float x) {
    return x * __builtin_amdgcn_rcpf(1.f + __expf(-x));
}

// ---------------- precompute: folded weight products ----------------
// Minp = w_inproj @ w_proj (512x12); M2T[k][o] = (w_ih @ w_out)[o][k] TRANSPOSED
// so k_xg's global reads are lane-coalesced. c2 = b_ih + b_hh; Ab = -exp(A_log).
__global__ void k_pre(const float* w_proj, const float* b_proj, const float* w_inproj,
                      const float* A_log, const float* w_ih, const float* w_out,
                      const float* b_ih, const float* b_hh,
                      float* Ab, float* Minp, float* cinp, float* M2T, float* c2) {
    int idx = blockIdx.x * 256 + threadIdx.x;
    if (idx < 4096) {
        Ab[idx] = -expf(A_log[idx]);
    } else if (idx < 4096 + 6144) {
        int j = idx - 4096; int o = j / 12; int i = j - o * 12;
        float s = 0.f;
        for (int k = 0; k < 128; ++k) s += w_inproj[o*128+k] * w_proj[k*12+i];
        Minp[j] = s;
    } else if (idx < 4096 + 6144 + 512) {
        int o = idx - (4096 + 6144);
        float s = 0.f;
        for (int k = 0; k < 128; ++k) s += w_inproj[o*128+k] * b_proj[k];
        cinp[o] = s;
    } else if (idx < 4096 + 6144 + 512 + 131072) {
        int j = idx - (4096 + 6144 + 512);
        int o = j >> 8; int dd = j & 255;
        float s = 0.f;
        for (int k = 0; k < 128; ++k) s += w_ih[o*128+k] * w_out[k*256+dd];
        M2T[dd*512 + o] = s;    // transposed store
    } else if (idx < 4096 + 6144 + 512 + 131072 + 512) {
        int o = idx - (4096 + 6144 + 512 + 131072);
        c2[o] = b_ih[o] + b_hh[o];
    }
}

// ---------------- k_front: fused inproj + depthwise conv + SiLU ----------------
__global__ void __launch_bounds__(256) k_front(const float* __restrict__ x,
                       const float* __restrict__ Minp, const float* __restrict__ cinp,
                       const float* __restrict__ conv_w, const float* __restrict__ conv_b,
                       float* __restrict__ uc, float* __restrict__ zb) {
    __shared__ float xs[67*12];
    int b = blockIdx.x >> 4;
    int c = blockIdx.x & 15;
    int d = threadIdx.x;
    int t0 = c * 64;
    for (int i = d; i < 67*12; i += 256) {
        int trel = i / 12;
        int t = t0 - 3 + trel;
        xs[i] = (t >= 0) ? x[(b*1024 + t)*12 + (i - trel*12)] : 0.f;
    }
    __syncthreads();
    float mu[12], mz[12];
#pragma unroll
    for (int i = 0; i < 12; ++i) { mu[i] = Minp[d*12 + i]; mz[i] = Minp[(256+d)*12 + i]; }
    float cu = cinp[d], cz = cinp[256 + d];
    float cw0 = conv_w[d*4+0], cw1 = conv_w[d*4+1], cw2 = conv_w[d*4+2], cw3 = conv_w[d*4+3];
    float cb = conv_b[d];
    float r0 = 0.f, r1 = 0.f, r2 = 0.f;
#pragma unroll
    for (int k = 0; k < 3; ++k) {
        int t = t0 - 3 + k;
        float v = 0.f;
        if (t >= 0) {
            const float* xr = &xs[k*12];
            v = cu;
#pragma unroll
            for (int i = 0; i < 12; ++i) v += mu[i]*xr[i];
        }
        r0 = r1; r1 = r2; r2 = v;
    }
    for (int t = t0; t < t0 + 64; ++t) {
        const float* xr = &xs[(t - t0 + 3)*12];
        float u = cu, z = cz;
#pragma unroll
        for (int i = 0; i < 12; ++i) { u += mu[i]*xr[i]; z += mz[i]*xr[i]; }
        float cv = cb + cw0*r0 + cw1*r1 + cw2*r2 + cw3*u;
        uc[(b*1024 + t)*256 + d] = fsilu(cv);
        zb[(b*1024 + t)*256 + d] = z;
        r0 = r1; r1 = r2; r2 = u;
    }
}

// ---------------- k3: xdbc = uc @ w_xproj^T; dt = softplus(...) ----------------
__global__ void __launch_bounds__(256) k_xproj(const float* __restrict__ uc,
                        const float* __restrict__ w_xproj, const float* __restrict__ w_dt,
                        const float* __restrict__ b_dt,
                        float* __restrict__ dtb, float* __restrict__ Bm, float* __restrict__ Cm) {
    __shared__ float ur[256];
    __shared__ float xd[40];
    int tok = blockIdx.x;
    int tid = threadIdx.x;
    ur[tid] = uc[tok*256 + tid];
    __syncthreads();
    int j = tid >> 2, q = tid & 3;
    float s = 0.f;
    if (j < 40) {
        const float* wr = w_xproj + j*256 + q*64;
        const float* uq = ur + q*64;
#pragma unroll 8
        for (int k = 0; k < 64; ++k) s += wr[k] * uq[k];
    }
    s += __shfl_xor(s, 1);
    s += __shfl_xor(s, 2);
    if (j < 40 && q == 0) {
        xd[j] = s;
        if (j >= 8 && j < 24)      Bm[tok*16 + (j - 8)]  = s;
        else if (j >= 24)          Cm[tok*16 + (j - 24)] = s;
    }
    __syncthreads();
    float r = b_dt[tid];
    const float* wd = w_dt + tid*8;
#pragma unroll
    for (int jj = 0; jj < 8; ++jj) r += wd[jj] * xd[jj];
    r = (r > 20.f) ? r : log1pf(expf(r));   // softplus
    dtb[tok*256 + tid] = r;
}

// ---------------- SSM chunked scan ----------------
__global__ void __launch_bounds__(256) k_ssm_p1(const float* __restrict__ dtb,
                        const float* __restrict__ uc, const float* __restrict__ Bm,
                        const float* __restrict__ Ab,
                        float* __restrict__ h0end, float* __restrict__ Ssum) {
    __shared__ float Bs[CHUNK*16];
    int b = blockIdx.x >> 4;
    int c = blockIdx.x & 15;
    int d = threadIdx.x;
    int t0 = c * CHUNK;
    {
        const float* src = Bm + (b*1024 + t0) * 16;
        for (int i = d; i < CHUNK*16; i += 256) Bs[i] = src[i];
    }
    __syncthreads();
    float a[16], h[16];
#pragma unroll
    for (int s = 0; s < 16; ++s) { a[s] = Ab[d*16+s]; h[s] = 0.f; }
    float S = 0.f;
    const float* dtp = dtb + (b*1024 + t0)*256 + d;
    const float* up  = uc  + (b*1024 + t0)*256 + d;
    float dtv = dtp[0], uv = up[0];
    for (int t = 0; t < CHUNK; ++t) {
        float dtn = 0.f, un = 0.f;
        if (t < CHUNK-1) { dtn = dtp[(t+1)*256]; un = up[(t+1)*256]; }
        float dtu = dtv * uv;
        S += dtv;
#pragma unroll
        for (int s = 0; s < 16; ++s) {
            float dA = __expf(dtv * a[s]);
            h[s] = h[s]*dA + dtu * Bs[t*16+s];
        }
        dtv = dtn; uv = un;
    }
    float* he = h0end + ((b*256 + d)*16 + c)*16;
#pragma unroll
    for (int s = 0; s < 16; ++s) he[s] = h[s];
    Ssum[(b*256 + d)*16 + c] = S;
}

__global__ void k_ssm_p2(const float* __restrict__ h0end, const float* __restrict__ Ssum,
                         const float* __restrict__ Ab, float* __restrict__ hinit) {
    int gid = blockIdx.x * 256 + threadIdx.x;   // 131072 = 32*256*16
    int s = gid & 15;
    int bd = gid >> 4;
    int d = bd & 255;
    float a = Ab[d*16 + s];
    float carry = 0.f;
    const float* he = h0end + bd * 256;
    float* hi = hinit + bd * 256;
    const float* Sp = Ssum + bd * 16;
    for (int c = 0; c < 16; ++c) {
        hi[c*16 + s] = carry;
        carry = he[c*16 + s] + __expf(a * Sp[c]) * carry;
    }
}

__global__ void __launch_bounds__(256) k_ssm_p3(const float* __restrict__ dtb,
                        const float* __restrict__ uc, const float* __restrict__ zb,
                        const float* __restrict__ Bm, const float* __restrict__ Cm,
                        const float* __restrict__ Ab, const float* __restrict__ Dskip,
                        const float* __restrict__ hinit, float* __restrict__ yg) {
    __shared__ float Bs[CHUNK*16];
    __shared__ float Cs[CHUNK*16];
    int b = blockIdx.x >> 4;
    int c = blockIdx.x & 15;
    int d = threadIdx.x;
    int t0 = c * CHUNK;
    {
        const float* srcB = Bm + (b*1024 + t0) * 16;
        const float* srcC = Cm + (b*1024 + t0) * 16;
        for (int i = d; i < CHUNK*16; i += 256) { Bs[i] = srcB[i]; Cs[i] = srcC[i]; }
    }
    __syncthreads();
    float a[16], h[16];
    const float* hi = hinit + ((b*256 + d)*16 + c)*16;
#pragma unroll
    for (int s = 0; s < 16; ++s) { a[s] = Ab[d*16+s]; h[s] = hi[s]; }
    float Dv = Dskip[d];
    const float* dtp = dtb + (b*1024 + t0)*256 + d;
    const float* up  = uc  + (b*1024 + t0)*256 + d;
    const float* zp  = zb  + (b*1024 + t0)*256 + d;
    float* yp = yg + (b*1024 + t0)*256 + d;
    float dtv = dtp[0], uv = up[0], zv = zp[0];
    for (int t = 0; t < CHUNK; ++t) {
        float dtn = 0.f, un = 0.f, zn = 0.f;
        if (t < CHUNK-1) { dtn = dtp[(t+1)*256]; un = up[(t+1)*256]; zn = zp[(t+1)*256]; }
        float dtu = dtv * uv;
        float y = 0.f;
#pragma unroll
        for (int s = 0; s < 16; ++s) {
            float dA = __expf(dtv * a[s]);
            h[s] = h[s]*dA + dtu * Bs[t*16+s];
            y += h[s] * Cs[t*16+s];
        }
        yp[t*256] = (y + uv * Dv) * fsilu(zv);
        dtv = dtn; uv = un; zv = zn;
    }
}

// ---------------- k5: xg = yg @ M2^T + c2  via transposed M2T, coalesced ----
// Thread tid owns outputs o0=tid, o1=tid+256 for 16 tokens. Per k: two
// lane-coalesced global reads of M2T[k][*] (L2-resident, 512 KB) and 16
// same-address LDS broadcasts of ytile[r][k]. FMA-issue-bound.
__global__ void __launch_bounds__(256) k_xg(const float* __restrict__ yg,
                      const float* __restrict__ M2T, const float* __restrict__ c2,
                      float* __restrict__ xg) {
    __shared__ float ytile[16][257];
    int tokbase = blockIdx.x * 16;
    int tid = threadIdx.x;
    for (int r = 0; r < 16; ++r) ytile[r][tid] = yg[(tokbase + r)*256 + tid];
    __syncthreads();
    int o0 = tid, o1 = tid + 256;
    float acc0[16], acc1[16];
    float cc0 = c2[o0], cc1 = c2[o1];
#pragma unroll
    for (int r = 0; r < 16; ++r) { acc0[r] = cc0; acc1[r] = cc1; }
#pragma unroll 4
    for (int k = 0; k < 256; ++k) {
        float m0 = M2T[k*512 + o0];
        float m1 = M2T[k*512 + o1];
#pragma unroll
        for (int r = 0; r < 16; ++r) {
            float yv = ytile[r][k];
            acc0[r] = fmaf(yv, m0, acc0[r]);
            acc1[r] = fmaf(yv, m1, acc1[r]);
        }
    }
    for (int r = 0; r < 16; ++r) {
        xg[(tokbase + r)*512 + o0] = acc0[r];
        xg[(tokbase + r)*512 + o1] = acc1[r];
    }
}

// ---------------- k6: LSTM (one block per batch) + FC head ----------------
// 1024 threads: thread = (gate o = tid>>1, k-half q = tid&1). 64 weights in
// 16 NAMED float4 regs: named (R4 proved arrays get scratch-demoted; R3's
// w[64] array -> VGPR 48 = spill) AND under the compiler's ~128-VGPR budget
// (R4/R5 showed 128 floats never fit: VGPR pinned 124 = re-read every step).
// ~95 VGPR demand < 128 budget (4 waves/SIMD forced by 1024-thread block).
#define LSTM_LOADW(i) float4 W##i = wr[i];
#define LSTM_DOT(i, acc) { float4 hv = h4[i]; \
    acc = fmaf(hv.x, W##i.x, acc); acc = fmaf(hv.y, W##i.y, acc); \
    acc = fmaf(hv.z, W##i.z, acc); acc = fmaf(hv.w, W##i.w, acc); }

__global__ void __launch_bounds__(1024) k_lstm(const float* __restrict__ xg,
                       const float* __restrict__ w_hh,
                       const float* __restrict__ w_fc1, const float* __restrict__ b_fc1,
                       const float* __restrict__ w_fc2, const float* __restrict__ b_fc2,
                       float* __restrict__ out) {
    __shared__ float hbuf[128];
    __shared__ float gbuf[512];
    int b = blockIdx.x;
    int tid = threadIdx.x;
    int o = tid >> 1, q = tid & 1;
    const float4* wr = (const float4*)(w_hh + o*128 + q*64);
    LSTM_LOADW(0)  LSTM_LOADW(1)  LSTM_LOADW(2)  LSTM_LOADW(3)
    LSTM_LOADW(4)  LSTM_LOADW(5)  LSTM_LOADW(6)  LSTM_LOADW(7)
    LSTM_LOADW(8)  LSTM_LOADW(9)  LSTM_LOADW(10) LSTM_LOADW(11)
    LSTM_LOADW(12) LSTM_LOADW(13) LSTM_LOADW(14) LSTM_LOADW(15)
    float cstate = 0.f;
    if (tid < 128) hbuf[tid] = 0.f;
    __syncthreads();
    const float* xgb = xg + (size_t)b * 1024 * 512;
    float gx = xgb[o];
    for (int t = 0; t < 1024; ++t) {
        float gxn = (t < 1023) ? xgb[(t+1)*512 + o] : 0.f;   // prefetch next step
        const float4* h4 = (const float4*)(hbuf + q*64);
        float a0 = 0.f, a1 = 0.f, a2 = 0.f, a3 = 0.f;
        LSTM_DOT(0,  a0) LSTM_DOT(4,  a1) LSTM_DOT(8,  a2) LSTM_DOT(12, a3)
        LSTM_DOT(1,  a0) LSTM_DOT(5,  a1) LSTM_DOT(9,  a2) LSTM_DOT(13, a3)
        LSTM_DOT(2,  a0) LSTM_DOT(6,  a1) LSTM_DOT(10, a2) LSTM_DOT(14, a3)
        LSTM_DOT(3,  a0) LSTM_DOT(7,  a1) LSTM_DOT(11, a2) LSTM_DOT(15, a3)
        float acc = (a0 + a1) + (a2 + a3);
        acc += __shfl_xor(acc, 1);            // combine q=0 / q=1 halves
        if (q == 0) gbuf[o] = gx + acc;
        __syncthreads();
        if (tid < 128) {
            float ig = fsig(gbuf[tid]);
            float fg = fsig(gbuf[tid+128]);
            float gg = ftanh(gbuf[tid+256]);
            float og = fsig(gbuf[tid+384]);
            cstate = fg*cstate + ig*gg;
            hbuf[tid] = og * ftanh(cstate);
        }
        __syncthreads();
        gx = gxn;
    }
    // FC head
    if (tid < 128) {
        float s = b_fc1[tid];
        const float* wf = w_fc1 + tid*128;
#pragma unroll 4
        for (int k = 0; k < 128; ++k) s += wf[k] * hbuf[k];
        gbuf[tid] = fmaxf(s, 0.f);
    }
    __syncthreads();
    if (tid < 5) {
        float s = b_fc2[tid];
        const float* wf = w_fc2 + tid*128;
        for (int k = 0; k < 128; ++k) s += wf[k] * gbuf[k];
        out[b*5 + tid] = s;
    }
}

// ---------------- launch ----------------
extern "C" void kernel_launch(void* const* d_in, const int* in_sizes, int n_in,
                              void* d_out, int out_size, void* d_ws, size_t ws_size,
                              hipStream_t stream) {
    const float* x        = (const float*)d_in[0];
    const float* w_proj   = (const float*)d_in[1];
    const float* b_proj   = (const float*)d_in[2];
    const float* w_inproj = (const float*)d_in[3];
    const float* conv_w   = (const float*)d_in[4];
    const float* conv_b   = (const float*)d_in[5];
    const float* w_xproj  = (const float*)d_in[6];
    const float* w_dt     = (const float*)d_in[7];
    const float* b_dt     = (const float*)d_in[8];
    const float* A_log    = (const float*)d_in[9];
    const float* Dskip    = (const float*)d_in[10];
    const float* w_out    = (const float*)d_in[11];
    const float* w_ih     = (const float*)d_in[12];
    const float* w_hh     = (const float*)d_in[13];
    const float* b_ih     = (const float*)d_in[14];
    const float* b_hh     = (const float*)d_in[15];
    const float* w_fc1    = (const float*)d_in[16];
    const float* b_fc1    = (const float*)d_in[17];
    const float* w_fc2    = (const float*)d_in[18];
    const float* b_fc2    = (const float*)d_in[19];
    float* outp = (float*)d_out;

    float* ws = (float*)d_ws;
    size_t off = 0;
    float* uc   = ws + off; off += 8388608;   // xg aliases uc+zb after p3
    float* zb   = ws + off; off += 8388608;
    float* dtb  = ws + off; off += 8388608;
    float* yg   = ws + off; off += 8388608;
    float* Bm   = ws + off; off += 524288;
    float* Cm   = ws + off; off += 524288;
    float* Ab   = ws + off; off += 4096;
    float* Minp = ws + off; off += 6144;
    float* cinp = ws + off; off += 512;
    float* M2T  = ws + off; off += 131072;
    float* c2   = ws + off; off += 512;
    float* h0end = ws + off; off += 2097152;
    float* Ssum  = ws + off; off += 131072;
    float* hinit = ws + off; off += 2097152;
    float* xg = uc;    // alias: spans uc+zb (16.7M floats), both dead after ssm_p3

    k_pre<<<556, 256, 0, stream>>>(w_proj, b_proj, w_inproj, A_log, w_ih, w_out,
                                   b_ih, b_hh, Ab, Minp, cinp, M2T, c2);
    k_front<<<512, 256, 0, stream>>>(x, Minp, cinp, conv_w, conv_b, uc, zb);
    k_xproj<<<32768, 256, 0, stream>>>(uc, w_xproj, w_dt, b_dt, dtb, Bm, Cm);
    k_ssm_p1<<<512, 256, 0, stream>>>(dtb, uc, Bm, Ab, h0end, Ssum);
    k_ssm_p2<<<512, 256, 0, stream>>>(h0end, Ssum, Ab, hinit);
    k_ssm_p3<<<512, 256, 0, stream>>>(dtb, uc, zb, Bm, Cm, Ab, Dskip, hinit, yg);
    k_xg<<<2048, 256, 0, stream>>>(yg, M2T, c2, xg);
    k_lstm<<<32, 1024, 0, stream>>>(xg, w_hh, w_fc1, b_fc1, w_fc2, b_fc2, outp);
}

// Round 7
// 1623.154 us; speedup vs baseline: 1.0887x; 1.0273x over previous
//
#include <hip/hip_runtime.h>
#include <math.h>

#define Bsz 32
#define Lseq 1024
#define CHUNK 64
#define NCHUNK 16

__device__ __forceinline__ float fsig(float x) {
    return __builtin_amdgcn_rcpf(1.f + __expf(-x));
}
// Accurate fast tanh: Taylor for small |x| (avoids catastrophic cancellation
// in the exp form at x~1e-7, which killed R2), exp form for large |x|.
__device__ __forceinline__ float ftanh(float x) {
    float x2 = x * x;
    float poly = x * (1.f - 0.333333333f * x2 + 0.133333333f * x2 * x2);
    float big = 1.f - 2.f * __builtin_amdgcn_rcpf(1.f + __expf(2.f * x));
    return (x2 < 0.0025f) ? poly : big;
}
__device__ __forceinline__ float fsilu(float x) {
    return x * __builtin_amdgcn_rcpf(1.f + __expf(-x));
}

// ---------------- precompute: folded weight products ----------------
// Minp = w_inproj @ w_proj (512x12); M2T[k][o] = (w_ih @ w_out)[o][k] TRANSPOSED
// so k_xg's global reads are lane-coalesced. c2 = b_ih + b_hh; Ab = -exp(A_log).
__global__ void k_pre(const float* w_proj, const float* b_proj, const float* w_inproj,
                      const float* A_log, const float* w_ih, const float* w_out,
                      const float* b_ih, const float* b_hh,
                      float* Ab, float* Minp, float* cinp, float* M2T, float* c2) {
    int idx = blockIdx.x * 256 + threadIdx.x;
    if (idx < 4096) {
        Ab[idx] = -expf(A_log[idx]);
    } else if (idx < 4096 + 6144) {
        int j = idx - 4096; int o = j / 12; int i = j - o * 12;
        float s = 0.f;
        for (int k = 0; k < 128; ++k) s += w_inproj[o*128+k] * w_proj[k*12+i];
        Minp[j] = s;
    } else if (idx < 4096 + 6144 + 512) {
        int o = idx - (4096 + 6144);
        float s = 0.f;
        for (int k = 0; k < 128; ++k) s += w_inproj[o*128+k] * b_proj[k];
        cinp[o] = s;
    } else if (idx < 4096 + 6144 + 512 + 131072) {
        int j = idx - (4096 + 6144 + 512);
        int o = j >> 8; int dd = j & 255;
        float s = 0.f;
        for (int k = 0; k < 128; ++k) s += w_ih[o*128+k] * w_out[k*256+dd];
        M2T[dd*512 + o] = s;    // transposed store
    } else if (idx < 4096 + 6144 + 512 + 131072 + 512) {
        int o = idx - (4096 + 6144 + 512 + 131072);
        c2[o] = b_ih[o] + b_hh[o];
    }
}

// ---------------- k_front: fused inproj + depthwise conv + SiLU ----------------
__global__ void __launch_bounds__(256) k_front(const float* __restrict__ x,
                       const float* __restrict__ Minp, const float* __restrict__ cinp,
                       const float* __restrict__ conv_w, const float* __restrict__ conv_b,
                       float* __restrict__ uc, float* __restrict__ zb) {
    __shared__ float xs[67*12];
    int b = blockIdx.x >> 4;
    int c = blockIdx.x & 15;
    int d = threadIdx.x;
    int t0 = c * 64;
    for (int i = d; i < 67*12; i += 256) {
        int trel = i / 12;
        int t = t0 - 3 + trel;
        xs[i] = (t >= 0) ? x[(b*1024 + t)*12 + (i - trel*12)] : 0.f;
    }
    __syncthreads();
    float mu[12], mz[12];
#pragma unroll
    for (int i = 0; i < 12; ++i) { mu[i] = Minp[d*12 + i]; mz[i] = Minp[(256+d)*12 + i]; }
    float cu = cinp[d], cz = cinp[256 + d];
    float cw0 = conv_w[d*4+0], cw1 = conv_w[d*4+1], cw2 = conv_w[d*4+2], cw3 = conv_w[d*4+3];
    float cb = conv_b[d];
    float r0 = 0.f, r1 = 0.f, r2 = 0.f;
#pragma unroll
    for (int k = 0; k < 3; ++k) {
        int t = t0 - 3 + k;
        float v = 0.f;
        if (t >= 0) {
            const float* xr = &xs[k*12];
            v = cu;
#pragma unroll
            for (int i = 0; i < 12; ++i) v += mu[i]*xr[i];
        }
        r0 = r1; r1 = r2; r2 = v;
    }
    for (int t = t0; t < t0 + 64; ++t) {
        const float* xr = &xs[(t - t0 + 3)*12];
        float u = cu, z = cz;
#pragma unroll
        for (int i = 0; i < 12; ++i) { u += mu[i]*xr[i]; z += mz[i]*xr[i]; }
        float cv = cb + cw0*r0 + cw1*r1 + cw2*r2 + cw3*u;
        uc[(b*1024 + t)*256 + d] = fsilu(cv);
        zb[(b*1024 + t)*256 + d] = z;
        r0 = r1; r1 = r2; r2 = u;
    }
}

// ---------------- k3: xdbc = uc @ w_xproj^T; dt = softplus(...) ----------------
__global__ void __launch_bounds__(256) k_xproj(const float* __restrict__ uc,
                        const float* __restrict__ w_xproj, const float* __restrict__ w_dt,
                        const float* __restrict__ b_dt,
                        float* __restrict__ dtb, float* __restrict__ Bm, float* __restrict__ Cm) {
    __shared__ float ur[256];
    __shared__ float xd[40];
    int tok = blockIdx.x;
    int tid = threadIdx.x;
    ur[tid] = uc[tok*256 + tid];
    __syncthreads();
    int j = tid >> 2, q = tid & 3;
    float s = 0.f;
    if (j < 40) {
        const float* wr = w_xproj + j*256 + q*64;
        const float* uq = ur + q*64;
#pragma unroll 8
        for (int k = 0; k < 64; ++k) s += wr[k] * uq[k];
    }
    s += __shfl_xor(s, 1);
    s += __shfl_xor(s, 2);
    if (j < 40 && q == 0) {
        xd[j] = s;
        if (j >= 8 && j < 24)      Bm[tok*16 + (j - 8)]  = s;
        else if (j >= 24)          Cm[tok*16 + (j - 24)] = s;
    }
    __syncthreads();
    float r = b_dt[tid];
    const float* wd = w_dt + tid*8;
#pragma unroll
    for (int jj = 0; jj < 8; ++jj) r += wd[jj] * xd[jj];
    r = (r > 20.f) ? r : log1pf(expf(r));   // softplus
    dtb[tok*256 + tid] = r;
}

// ---------------- SSM chunked scan ----------------
__global__ void __launch_bounds__(256) k_ssm_p1(const float* __restrict__ dtb,
                        const float* __restrict__ uc, const float* __restrict__ Bm,
                        const float* __restrict__ Ab,
                        float* __restrict__ h0end, float* __restrict__ Ssum) {
    __shared__ float Bs[CHUNK*16];
    int b = blockIdx.x >> 4;
    int c = blockIdx.x & 15;
    int d = threadIdx.x;
    int t0 = c * CHUNK;
    {
        const float* src = Bm + (b*1024 + t0) * 16;
        for (int i = d; i < CHUNK*16; i += 256) Bs[i] = src[i];
    }
    __syncthreads();
    float a[16], h[16];
#pragma unroll
    for (int s = 0; s < 16; ++s) { a[s] = Ab[d*16+s]; h[s] = 0.f; }
    float S = 0.f;
    const float* dtp = dtb + (b*1024 + t0)*256 + d;
    const float* up  = uc  + (b*1024 + t0)*256 + d;
    float dtv = dtp[0], uv = up[0];
    for (int t = 0; t < CHUNK; ++t) {
        float dtn = 0.f, un = 0.f;
        if (t < CHUNK-1) { dtn = dtp[(t+1)*256]; un = up[(t+1)*256]; }
        float dtu = dtv * uv;
        S += dtv;
#pragma unroll
        for (int s = 0; s < 16; ++s) {
            float dA = __expf(dtv * a[s]);
            h[s] = h[s]*dA + dtu * Bs[t*16+s];
        }
        dtv = dtn; uv = un;
    }
    float* he = h0end + ((b*256 + d)*16 + c)*16;
#pragma unroll
    for (int s = 0; s < 16; ++s) he[s] = h[s];
    Ssum[(b*256 + d)*16 + c] = S;
}

__global__ void k_ssm_p2(const float* __restrict__ h0end, const float* __restrict__ Ssum,
                         const float* __restrict__ Ab, float* __restrict__ hinit) {
    int gid = blockIdx.x * 256 + threadIdx.x;   // 131072 = 32*256*16
    int s = gid & 15;
    int bd = gid >> 4;
    int d = bd & 255;
    float a = Ab[d*16 + s];
    float carry = 0.f;
    const float* he = h0end + bd * 256;
    float* hi = hinit + bd * 256;
    const float* Sp = Ssum + bd * 16;
    for (int c = 0; c < 16; ++c) {
        hi[c*16 + s] = carry;
        carry = he[c*16 + s] + __expf(a * Sp[c]) * carry;
    }
}

__global__ void __launch_bounds__(256) k_ssm_p3(const float* __restrict__ dtb,
                        const float* __restrict__ uc, const float* __restrict__ zb,
                        const float* __restrict__ Bm, const float* __restrict__ Cm,
                        const float* __restrict__ Ab, const float* __restrict__ Dskip,
                        const float* __restrict__ hinit, float* __restrict__ yg) {
    __shared__ float Bs[CHUNK*16];
    __shared__ float Cs[CHUNK*16];
    int b = blockIdx.x >> 4;
    int c = blockIdx.x & 15;
    int d = threadIdx.x;
    int t0 = c * CHUNK;
    {
        const float* srcB = Bm + (b*1024 + t0) * 16;
        const float* srcC = Cm + (b*1024 + t0) * 16;
        for (int i = d; i < CHUNK*16; i += 256) { Bs[i] = srcB[i]; Cs[i] = srcC[i]; }
    }
    __syncthreads();
    float a[16], h[16];
    const float* hi = hinit + ((b*256 + d)*16 + c)*16;
#pragma unroll
    for (int s = 0; s < 16; ++s) { a[s] = Ab[d*16+s]; h[s] = hi[s]; }
    float Dv = Dskip[d];
    const float* dtp = dtb + (b*1024 + t0)*256 + d;
    const float* up  = uc  + (b*1024 + t0)*256 + d;
    const float* zp  = zb  + (b*1024 + t0)*256 + d;
    float* yp = yg + (b*1024 + t0)*256 + d;
    float dtv = dtp[0], uv = up[0], zv = zp[0];
    for (int t = 0; t < CHUNK; ++t) {
        float dtn = 0.f, un = 0.f, zn = 0.f;
        if (t < CHUNK-1) { dtn = dtp[(t+1)*256]; un = up[(t+1)*256]; zn = zp[(t+1)*256]; }
        float dtu = dtv * uv;
        float y = 0.f;
#pragma unroll
        for (int s = 0; s < 16; ++s) {
            float dA = __expf(dtv * a[s]);
            h[s] = h[s]*dA + dtu * Bs[t*16+s];
            y += h[s] * Cs[t*16+s];
        }
        yp[t*256] = (y + uv * Dv) * fsilu(zv);
        dtv = dtn; uv = un; zv = zn;
    }
}

// ---------------- k5: xg = yg @ M2^T + c2  via transposed M2T, coalesced ----
__global__ void __launch_bounds__(256) k_xg(const float* __restrict__ yg,
                      const float* __restrict__ M2T, const float* __restrict__ c2,
                      float* __restrict__ xg) {
    __shared__ float ytile[16][257];
    int tokbase = blockIdx.x * 16;
    int tid = threadIdx.x;
    for (int r = 0; r < 16; ++r) ytile[r][tid] = yg[(tokbase + r)*256 + tid];
    __syncthreads();
    int o0 = tid, o1 = tid + 256;
    float acc0[16], acc1[16];
    float cc0 = c2[o0], cc1 = c2[o1];
#pragma unroll
    for (int r = 0; r < 16; ++r) { acc0[r] = cc0; acc1[r] = cc1; }
#pragma unroll 4
    for (int k = 0; k < 256; ++k) {
        float m0 = M2T[k*512 + o0];
        float m1 = M2T[k*512 + o1];
#pragma unroll
        for (int r = 0; r < 16; ++r) {
            float yv = ytile[r][k];
            acc0[r] = fmaf(yv, m0, acc0[r]);
            acc1[r] = fmaf(yv, m1, acc1[r]);
        }
    }
    for (int r = 0; r < 16; ++r) {
        xg[(tokbase + r)*512 + o0] = acc0[r];
        xg[(tokbase + r)*512 + o1] = acc1[r];
    }
}

// ---------------- k6: LSTM (one block per batch) + FC head ----------------
// 512 threads, thread = gate output o, full 128-wide w_hh row in 32 NAMED
// float4s. The allocator's VGPR budget is set by amdgpu_waves_per_eu, NOT
// __launch_bounds__'s 2nd arg (R1/R4/R5/R6: budget pinned at <=124 -> weights
// re-read from L2 every step, ~2900 cyc/step). A 512-thread block needs
// exactly 2 waves/EU to be resident, so (2,2) is feasible and sets budget =
// 512/2 = 256 VGPRs >= ~165 demand -> weights stay register-resident.
#define LSTM_LOADW(i) float4 W##i = wr[i];
#define LSTM_DOT(i, acc) { float4 hv = h4[i]; \
    acc = fmaf(hv.x, W##i.x, acc); acc = fmaf(hv.y, W##i.y, acc); \
    acc = fmaf(hv.z, W##i.z, acc); acc = fmaf(hv.w, W##i.w, acc); }

__global__ void __launch_bounds__(512)
__attribute__((amdgpu_waves_per_eu(2, 2)))
k_lstm(const float* __restrict__ xg,
                       const float* __restrict__ w_hh,
                       const float* __restrict__ w_fc1, const float* __restrict__ b_fc1,
                       const float* __restrict__ w_fc2, const float* __restrict__ b_fc2,
                       float* __restrict__ out) {
    __shared__ float hbuf[128];
    __shared__ float gbuf[512];
    int b = blockIdx.x;
    int tid = threadIdx.x;   // gate output index o
    const float4* wr = (const float4*)(w_hh + tid*128);
    LSTM_LOADW(0)  LSTM_LOADW(1)  LSTM_LOADW(2)  LSTM_LOADW(3)
    LSTM_LOADW(4)  LSTM_LOADW(5)  LSTM_LOADW(6)  LSTM_LOADW(7)
    LSTM_LOADW(8)  LSTM_LOADW(9)  LSTM_LOADW(10) LSTM_LOADW(11)
    LSTM_LOADW(12) LSTM_LOADW(13) LSTM_LOADW(14) LSTM_LOADW(15)
    LSTM_LOADW(16) LSTM_LOADW(17) LSTM_LOADW(18) LSTM_LOADW(19)
    LSTM_LOADW(20) LSTM_LOADW(21) LSTM_LOADW(22) LSTM_LOADW(23)
    LSTM_LOADW(24) LSTM_LOADW(25) LSTM_LOADW(26) LSTM_LOADW(27)
    LSTM_LOADW(28) LSTM_LOADW(29) LSTM_LOADW(30) LSTM_LOADW(31)
    float cstate = 0.f;
    if (tid < 128) hbuf[tid] = 0.f;
    __syncthreads();
    const float* xgb = xg + (size_t)b * 1024 * 512;
    float gx = xgb[tid];
    for (int t = 0; t < 1024; ++t) {
        float gxn = (t < 1023) ? xgb[(t+1)*512 + tid] : 0.f;   // prefetch next step
        const float4* h4 = (const float4*)hbuf;
        float a0 = 0.f, a1 = 0.f, a2 = 0.f, a3 = 0.f;
        LSTM_DOT(0,  a0) LSTM_DOT(8,  a1) LSTM_DOT(16, a2) LSTM_DOT(24, a3)
        LSTM_DOT(1,  a0) LSTM_DOT(9,  a1) LSTM_DOT(17, a2) LSTM_DOT(25, a3)
        LSTM_DOT(2,  a0) LSTM_DOT(10, a1) LSTM_DOT(18, a2) LSTM_DOT(26, a3)
        LSTM_DOT(3,  a0) LSTM_DOT(11, a1) LSTM_DOT(19, a2) LSTM_DOT(27, a3)
        LSTM_DOT(4,  a0) LSTM_DOT(12, a1) LSTM_DOT(20, a2) LSTM_DOT(28, a3)
        LSTM_DOT(5,  a0) LSTM_DOT(13, a1) LSTM_DOT(21, a2) LSTM_DOT(29, a3)
        LSTM_DOT(6,  a0) LSTM_DOT(14, a1) LSTM_DOT(22, a2) LSTM_DOT(30, a3)
        LSTM_DOT(7,  a0) LSTM_DOT(15, a1) LSTM_DOT(23, a2) LSTM_DOT(31, a3)
        gbuf[tid] = gx + ((a0 + a1) + (a2 + a3));
        __syncthreads();
        if (tid < 128) {
            float ig = fsig(gbuf[tid]);
            float fg = fsig(gbuf[tid+128]);
            float gg = ftanh(gbuf[tid+256]);
            float og = fsig(gbuf[tid+384]);
            cstate = fg*cstate + ig*gg;
            hbuf[tid] = og * ftanh(cstate);
        }
        __syncthreads();
        gx = gxn;
    }
    // FC head
    if (tid < 128) {
        float s = b_fc1[tid];
        const float* wf = w_fc1 + tid*128;
#pragma unroll 4
        for (int k = 0; k < 128; ++k) s += wf[k] * hbuf[k];
        gbuf[tid] = fmaxf(s, 0.f);
    }
    __syncthreads();
    if (tid < 5) {
        float s = b_fc2[tid];
        const float* wf = w_fc2 + tid*128;
        for (int k = 0; k < 128; ++k) s += wf[k] * gbuf[k];
        out[b*5 + tid] = s;
    }
}

// ---------------- launch ----------------
extern "C" void kernel_launch(void* const* d_in, const int* in_sizes, int n_in,
                              void* d_out, int out_size, void* d_ws, size_t ws_size,
                              hipStream_t stream) {
    const float* x        = (const float*)d_in[0];
    const float* w_proj   = (const float*)d_in[1];
    const float* b_proj   = (const float*)d_in[2];
    const float* w_inproj = (const float*)d_in[3];
    const float* conv_w   = (const float*)d_in[4];
    const float* conv_b   = (const float*)d_in[5];
    const float* w_xproj  = (const float*)d_in[6];
    const float* w_dt     = (const float*)d_in[7];
    const float* b_dt     = (const float*)d_in[8];
    const float* A_log    = (const float*)d_in[9];
    const float* Dskip    = (const float*)d_in[10];
    const float* w_out    = (const float*)d_in[11];
    const float* w_ih     = (const float*)d_in[12];
    const float* w_hh     = (const float*)d_in[13];
    const float* b_ih     = (const float*)d_in[14];
    const float* b_hh     = (const float*)d_in[15];
    const float* w_fc1    = (const float*)d_in[16];
    const float* b_fc1    = (const float*)d_in[17];
    const float* w_fc2    = (const float*)d_in[18];
    const float* b_fc2    = (const float*)d_in[19];
    float* outp = (float*)d_out;

    float* ws = (float*)d_ws;
    size_t off = 0;
    float* uc   = ws + off; off += 8388608;   // xg aliases uc+zb after p3
    float* zb   = ws + off; off += 8388608;
    float* dtb  = ws + off; off += 8388608;
    float* yg   = ws + off; off += 8388608;
    float* Bm   = ws + off; off += 524288;
    float* Cm   = ws + off; off += 524288;
    float* Ab   = ws + off; off += 4096;
    float* Minp = ws + off; off += 6144;
    float* cinp = ws + off; off += 512;
    float* M2T  = ws + off; off += 131072;
    float* c2   = ws + off; off += 512;
    float* h0end = ws + off; off += 2097152;
    float* Ssum  = ws + off; off += 131072;
    float* hinit = ws + off; off += 2097152;
    float* xg = uc;    // alias: spans uc+zb (16.7M floats), both dead after ssm_p3

    k_pre<<<556, 256, 0, stream>>>(w_proj, b_proj, w_inproj, A_log, w_ih, w_out,
                                   b_ih, b_hh, Ab, Minp, cinp, M2T, c2);
    k_front<<<512, 256, 0, stream>>>(x, Minp, cinp, conv_w, conv_b, uc, zb);
    k_xproj<<<32768, 256, 0, stream>>>(uc, w_xproj, w_dt, b_dt, dtb, Bm, Cm);
    k_ssm_p1<<<512, 256, 0, stream>>>(dtb, uc, Bm, Ab, h0end, Ssum);
    k_ssm_p2<<<512, 256, 0, stream>>>(h0end, Ssum, Ab, hinit);
    k_ssm_p3<<<512, 256, 0, stream>>>(dtb, uc, zb, Bm, Cm, Ab, Dskip, hinit, yg);
    k_xg<<<2048, 256, 0, stream>>>(yg, M2T, c2, xg);
    k_lstm<<<32, 512, 0, stream>>>(xg, w_hh, w_fc1, b_fc1, w_fc2, b_fc2, outp);
}